// Round 1
// baseline (128.874 us; speedup 1.0000x reference)
//
#include <hip/hip_runtime.h>

#define D  64
#define BM 128
#define BN 128

// ---------------------------------------------------------------------------
// Pre-pass: row squared-norms for x and y into workspace.
// sq[0..8191] = ||x_row||^2, sq[8192..16383] = ||y_row||^2.
// ---------------------------------------------------------------------------
__global__ __launch_bounds__(256) void rbf_rowsq(const float* __restrict__ x,
                                                 const float* __restrict__ y,
                                                 float* __restrict__ sq) {
    int tid = blockIdx.x * blockDim.x + threadIdx.x;  // 0..16383
    const float* src = (tid < 8192) ? x : y;
    int row = tid & 8191;
    const float4* p = reinterpret_cast<const float4*>(src + row * D);
    float s = 0.f;
#pragma unroll
    for (int i = 0; i < D / 4; ++i) {
        float4 v = p[i];
        s = fmaf(v.x, v.x, s);
        s = fmaf(v.y, v.y, s);
        s = fmaf(v.z, v.z, s);
        s = fmaf(v.w, v.w, s);
    }
    sq[tid] = s;
}

// ---------------------------------------------------------------------------
// Main kernel: 128x128 output tile per block, 256 threads, 8x8 per thread.
// LDS holds both tiles transposed: Xs[d][row], Ys[d][col] (stride 128 floats
// -> worst case 2-way bank aliasing on reads, which is free on CDNA4).
// dist2 = xsq + ysq - 2*dot;  out = exp(-dist2) (gamma = 1).
// ---------------------------------------------------------------------------
__global__ __launch_bounds__(256, 2) void rbf_main(const float* __restrict__ x,
                                                   const float* __restrict__ y,
                                                   const float* __restrict__ sq,
                                                   float* __restrict__ out) {
    __shared__ float Xs[D][BM];   // 32 KiB
    __shared__ float Ys[D][BN];   // 32 KiB  (total 64 KiB -> 2 blocks/CU)

    const int t    = threadIdx.x;
    const int bx   = blockIdx.x;           // col-tile (y rows)
    const int by   = blockIdx.y;           // row-tile (x rows)
    const int row0 = by * BM;
    const int col0 = bx * BN;

    // ---- stage both tiles, transposed ------------------------------------
    {
        const int r    = t & 127;          // lane-consecutive rows -> LDS
        const int half = t >> 7;           // write banks consecutive (no conflict)
        const float* xp = x + (size_t)(row0 + r) * D;
        const float* yp = y + (size_t)(col0 + r) * D;
#pragma unroll
        for (int it = 0; it < 8; ++it) {
            const int dv = half * 32 + it * 4;
            float4 gx = *reinterpret_cast<const float4*>(xp + dv);
            float4 gy = *reinterpret_cast<const float4*>(yp + dv);
            Xs[dv + 0][r] = gx.x; Xs[dv + 1][r] = gx.y;
            Xs[dv + 2][r] = gx.z; Xs[dv + 3][r] = gx.w;
            Ys[dv + 0][r] = gy.x; Ys[dv + 1][r] = gy.y;
            Ys[dv + 2][r] = gy.z; Ys[dv + 3][r] = gy.w;
        }
    }
    __syncthreads();

    const int tx = t & 15;
    const int ty = t >> 4;
    const int ra = ty * 4;   // thread rows: ra..ra+3, ra+64..ra+67
    const int ca = tx * 4;   // thread cols: ca..ca+3, ca+64..ca+67

    float acc[8][8];
#pragma unroll
    for (int i = 0; i < 8; ++i)
#pragma unroll
        for (int j = 0; j < 8; ++j) acc[i][j] = 0.f;

    // ---- main loop: 64 d-steps, 4x ds_read_b128 + 64 FMA per step --------
#pragma unroll 8
    for (int d = 0; d < D; ++d) {
        float4 xa = *reinterpret_cast<const float4*>(&Xs[d][ra]);
        float4 xb = *reinterpret_cast<const float4*>(&Xs[d][ra + 64]);
        float4 ya = *reinterpret_cast<const float4*>(&Ys[d][ca]);
        float4 yb = *reinterpret_cast<const float4*>(&Ys[d][ca + 64]);
        float xv[8] = {xa.x, xa.y, xa.z, xa.w, xb.x, xb.y, xb.z, xb.w};
        float yv[8] = {ya.x, ya.y, ya.z, ya.w, yb.x, yb.y, yb.z, yb.w};
#pragma unroll
        for (int i = 0; i < 8; ++i)
#pragma unroll
            for (int j = 0; j < 8; ++j)
                acc[i][j] = fmaf(xv[i], yv[j], acc[i][j]);
    }

    // ---- epilogue --------------------------------------------------------
    float xsq[8], ysq[8];
#pragma unroll
    for (int i = 0; i < 4; ++i) {
        xsq[i]     = sq[row0 + ra + i];
        xsq[i + 4] = sq[row0 + ra + 64 + i];
        ysq[i]     = sq[8192 + col0 + ca + i];
        ysq[i + 4] = sq[8192 + col0 + ca + 64 + i];
    }

#pragma unroll
    for (int i = 0; i < 8; ++i) {
        const int ri = row0 + ra + ((i < 4) ? i : (60 + i));  // +64 offset for hi half
        float* op = out + (size_t)ri * 8192 + col0;
        float4 o0, o1;
        {
            float v[4];
#pragma unroll
            for (int j = 0; j < 4; ++j) {
                float d2 = fmaxf(fmaf(-2.f, acc[i][j], xsq[i] + ysq[j]), 0.f);
                v[j] = __expf(-d2);
            }
            o0 = make_float4(v[0], v[1], v[2], v[3]);
        }
        {
            float v[4];
#pragma unroll
            for (int j = 0; j < 4; ++j) {
                float d2 = fmaxf(fmaf(-2.f, acc[i][j + 4], xsq[i] + ysq[j + 4]), 0.f);
                v[j] = __expf(-d2);
            }
            o1 = make_float4(v[0], v[1], v[2], v[3]);
        }
        *reinterpret_cast<float4*>(op + ca)      = o0;
        *reinterpret_cast<float4*>(op + ca + 64) = o1;
    }
}

extern "C" void kernel_launch(void* const* d_in, const int* in_sizes, int n_in,
                              void* d_out, int out_size, void* d_ws, size_t ws_size,
                              hipStream_t stream) {
    const float* x = (const float*)d_in[0];
    const float* y = (const float*)d_in[1];
    float* out = (float*)d_out;
    float* sq  = (float*)d_ws;   // 16384 floats = 64 KiB

    rbf_rowsq<<<64, 256, 0, stream>>>(x, y, sq);
    rbf_main<<<dim3(8192 / BN, 8192 / BM), 256, 0, stream>>>(x, y, sq, out);
}

// Round 2
// 72.693 us; speedup vs baseline: 1.7729x; 1.7729x over previous
//
#include <hip/hip_runtime.h>

#define D    64
#define BM   128
#define BN   128
#define NROW 8192

typedef _Float16 f16x8 __attribute__((ext_vector_type(8)));
typedef float    f32x4 __attribute__((ext_vector_type(4)));

// ---------------------------------------------------------------------------
// Pre-pass: row squared-norms (fp32, exact path) into workspace.
// sq[0..8191] = ||x_row||^2, sq[8192..16383] = ||y_row||^2.   (proven R1)
// ---------------------------------------------------------------------------
__global__ __launch_bounds__(256) void rbf_rowsq(const float* __restrict__ x,
                                                 const float* __restrict__ y,
                                                 float* __restrict__ sq) {
    int tid = blockIdx.x * blockDim.x + threadIdx.x;  // 0..16383
    const float* src = (tid < NROW) ? x : y;
    int row = tid & (NROW - 1);
    const float4* p = reinterpret_cast<const float4*>(src + row * D);
    float s = 0.f;
#pragma unroll
    for (int i = 0; i < D / 4; ++i) {
        float4 v = p[i];
        s = fmaf(v.x, v.x, s);
        s = fmaf(v.y, v.y, s);
        s = fmaf(v.z, v.z, s);
        s = fmaf(v.w, v.w, s);
    }
    sq[tid] = s;
}

// ---------------------------------------------------------------------------
// Main: 128x128 tile, 256 threads (4 waves). fp32 -> (f16 hi, f16 lo) split
// in-block into XOR-swizzled LDS; dot = hi*hi + hi*lo + lo*hi via
// mfma_f32_16x16x32_f16 (dropped lo*lo term ~1e-5 abs in dist^2).
// out = exp(-(xsq + ysq - 2*dot)).
// ---------------------------------------------------------------------------
__global__ __launch_bounds__(256, 2) void rbf_main(const float* __restrict__ x,
                                                   const float* __restrict__ y,
                                                   const float* __restrict__ sq,
                                                   float* __restrict__ out) {
    // 4 x 16 KiB planes: Xh, Xl, Yh, Yl   (f16[128 rows][64 d], row = 128 B)
    __shared__ __align__(16) char smem[65536];
    char* const XH = smem;
    char* const XL = smem + 16384;
    char* const YH = smem + 32768;
    char* const YL = smem + 49152;

    const int t    = threadIdx.x;
    const int row0 = blockIdx.y * BM;
    const int col0 = blockIdx.x * BN;

    // ---- stage + split-convert both tiles into swizzled LDS --------------
    {
        const int r    = t & 127;
        const int half = t >> 7;                 // d-halves 0..31 / 32..63
        const int swz  = (r & 7) << 4;           // 16B-granular XOR swizzle
        const int rowoff = r * 128;
        const float* xp = x + (size_t)(row0 + r) * D + half * 32;
        const float* yp = y + (size_t)(col0 + r) * D + half * 32;
#pragma unroll
        for (int it = 0; it < 4; ++it) {
            const int off = rowoff + ((half * 64 + it * 16) ^ swz);
            float4 a0 = *reinterpret_cast<const float4*>(xp + it * 8);
            float4 a1 = *reinterpret_cast<const float4*>(xp + it * 8 + 4);
            float4 b0 = *reinterpret_cast<const float4*>(yp + it * 8);
            float4 b1 = *reinterpret_cast<const float4*>(yp + it * 8 + 4);
            float xa[8] = {a0.x, a0.y, a0.z, a0.w, a1.x, a1.y, a1.z, a1.w};
            float yb[8] = {b0.x, b0.y, b0.z, b0.w, b1.x, b1.y, b1.z, b1.w};
            f16x8 xh, xl, yh, yl;
#pragma unroll
            for (int j = 0; j < 8; ++j) {
                _Float16 h = (_Float16)xa[j];
                xh[j] = h;
                xl[j] = (_Float16)(xa[j] - (float)h);
                _Float16 g = (_Float16)yb[j];
                yh[j] = g;
                yl[j] = (_Float16)(yb[j] - (float)g);
            }
            *reinterpret_cast<f16x8*>(XH + off) = xh;
            *reinterpret_cast<f16x8*>(XL + off) = xl;
            *reinterpret_cast<f16x8*>(YH + off) = yh;
            *reinterpret_cast<f16x8*>(YL + off) = yl;
        }
    }
    __syncthreads();

    const int lane = t & 63;
    const int w    = t >> 6;        // wave id 0..3 -> M-strip w*32
    const int l15  = lane & 15;
    const int lg   = lane >> 4;     // 0..3
    const int swz  = (l15 & 7) << 4;  // row&7 == l15&7 for all frag rows

    const int arow0 = w * 32 + l15;        // mt=0 A row
    const int arow1 = arow0 + 16;          // mt=1 A row

    f32x4 acc[2][8];
#pragma unroll
    for (int i = 0; i < 2; ++i)
#pragma unroll
        for (int j = 0; j < 8; ++j) acc[i][j] = (f32x4){0.f, 0.f, 0.f, 0.f};

    // ---- MFMA main: 2 K-halves x 8 N-tiles x 2 M-tiles x 3 products ------
#pragma unroll
    for (int kh = 0; kh < 2; ++kh) {
        const int dsw = (kh * 64 + lg * 16) ^ swz;
        f16x8 ah0 = *reinterpret_cast<const f16x8*>(XH + arow0 * 128 + dsw);
        f16x8 ah1 = *reinterpret_cast<const f16x8*>(XH + arow1 * 128 + dsw);
        f16x8 al0 = *reinterpret_cast<const f16x8*>(XL + arow0 * 128 + dsw);
        f16x8 al1 = *reinterpret_cast<const f16x8*>(XL + arow1 * 128 + dsw);
#pragma unroll
        for (int nt = 0; nt < 8; ++nt) {
            const int boff = (nt * 16 + l15) * 128 + dsw;
            f16x8 bh = *reinterpret_cast<const f16x8*>(YH + boff);
            f16x8 bl = *reinterpret_cast<const f16x8*>(YL + boff);
            acc[0][nt] = __builtin_amdgcn_mfma_f32_16x16x32_f16(ah0, bh, acc[0][nt], 0, 0, 0);
            acc[1][nt] = __builtin_amdgcn_mfma_f32_16x16x32_f16(ah1, bh, acc[1][nt], 0, 0, 0);
            acc[0][nt] = __builtin_amdgcn_mfma_f32_16x16x32_f16(ah0, bl, acc[0][nt], 0, 0, 0);
            acc[1][nt] = __builtin_amdgcn_mfma_f32_16x16x32_f16(ah1, bl, acc[1][nt], 0, 0, 0);
            acc[0][nt] = __builtin_amdgcn_mfma_f32_16x16x32_f16(al0, bh, acc[0][nt], 0, 0, 0);
            acc[1][nt] = __builtin_amdgcn_mfma_f32_16x16x32_f16(al1, bh, acc[1][nt], 0, 0, 0);
        }
    }

    // ---- epilogue: dist^2 -> exp -> store --------------------------------
    float xsqv[2][4], ysqv[8];
#pragma unroll
    for (int mt = 0; mt < 2; ++mt)
#pragma unroll
        for (int r = 0; r < 4; ++r)
            xsqv[mt][r] = sq[row0 + w * 32 + mt * 16 + lg * 4 + r];
#pragma unroll
    for (int nt = 0; nt < 8; ++nt)
        ysqv[nt] = sq[NROW + col0 + nt * 16 + l15];

#pragma unroll
    for (int mt = 0; mt < 2; ++mt) {
#pragma unroll
        for (int r = 0; r < 4; ++r) {
            const int rowg = row0 + w * 32 + mt * 16 + lg * 4 + r;
            float* op = out + (size_t)rowg * NROW + col0 + l15;
#pragma unroll
            for (int nt = 0; nt < 8; ++nt) {
                float d2 = fmaf(-2.f, acc[mt][nt][r], xsqv[mt][r] + ysqv[nt]);
                d2 = fmaxf(d2, 0.f);
                op[nt * 16] = __expf(-d2);
            }
        }
    }
}

extern "C" void kernel_launch(void* const* d_in, const int* in_sizes, int n_in,
                              void* d_out, int out_size, void* d_ws, size_t ws_size,
                              hipStream_t stream) {
    const float* x = (const float*)d_in[0];
    const float* y = (const float*)d_in[1];
    float* out = (float*)d_out;
    float* sq  = (float*)d_ws;   // 16384 floats = 64 KiB (proven in R1)

    rbf_rowsq<<<64, 256, 0, stream>>>(x, y, sq);
    rbf_main<<<dim3(NROW / BN, NROW / BM), 256, 0, stream>>>(x, y, sq, out);
}

// Round 3
// 67.216 us; speedup vs baseline: 1.9173x; 1.0815x over previous
//
#include <hip/hip_runtime.h>

#define D    64
#define NROW 8192

typedef _Float16 f16x8 __attribute__((ext_vector_type(8)));
typedef float    f32x4 __attribute__((ext_vector_type(4)));

// ---------------------------------------------------------------------------
// Fused RBF kernel. 128x128 output tile, 256 threads (4 waves).
//   - y tile staged in LDS as f16 hi/lo split (XOR-swizzled), + partial ysq.
//   - x fragments loaded direct from global per-wave, split in-register;
//     xsq via in-register partials + shfl_xor cross-lane reduce.
//   - MFMA with SWAPPED operands: A = y-frag (M dim = y cols), B = x-frag
//     (N dim = x rows). C/D map (verified R2): n = lane&15 -> x row,
//     m = (lane>>4)*4 + reg -> 4 CONSECUTIVE y cols -> float4 stores.
//   - dot = hi*hi + lo*hi + hi*lo (lo*lo dropped, ~1e-5 abs in dist^2,
//     measured absmax 4e-28 in R2 vs threshold 1.5e-20).
// ---------------------------------------------------------------------------
__global__ __launch_bounds__(256, 3) void rbf_fused(const float* __restrict__ x,
                                                    const float* __restrict__ y,
                                                    float* __restrict__ out) {
    __shared__ __align__(16) char YH[16384];   // f16[128 rows][64 d], swizzled
    __shared__ __align__(16) char YL[16384];
    __shared__ float Ysq0[128];                // partial ||y||^2, d 0..31
    __shared__ float Ysq1[128];                // partial ||y||^2, d 32..63

    const int t    = threadIdx.x;
    const int col0 = blockIdx.x * 128;   // y-col tile
    const int row0 = blockIdx.y * 128;   // x-row tile

    // ---- stage y tile: hi/lo split + partial squared norms ---------------
    {
        const int r    = t & 127;
        const int half = t >> 7;                 // d-halves 0..31 / 32..63
        const int swz  = (r & 7) << 4;
        const float* yp = y + (size_t)(col0 + r) * D + half * 32;
        float ssq = 0.f;
#pragma unroll
        for (int it = 0; it < 4; ++it) {
            float4 b0 = *reinterpret_cast<const float4*>(yp + it * 8);
            float4 b1 = *reinterpret_cast<const float4*>(yp + it * 8 + 4);
            float v[8] = {b0.x, b0.y, b0.z, b0.w, b1.x, b1.y, b1.z, b1.w};
            f16x8 h, l;
#pragma unroll
            for (int j = 0; j < 8; ++j) {
                _Float16 hh = (_Float16)v[j];
                h[j] = hh;
                l[j] = (_Float16)(v[j] - (float)hh);
                ssq  = fmaf(v[j], v[j], ssq);
            }
            const int off = r * 128 + ((half * 64 + it * 16) ^ swz);
            *reinterpret_cast<f16x8*>(YH + off) = h;
            *reinterpret_cast<f16x8*>(YL + off) = l;
        }
        if (half == 0) Ysq0[r] = ssq; else Ysq1[r] = ssq;
    }

    // ---- load x fragments direct from global, split in-register ----------
    const int lane = t & 63;
    const int w    = t >> 6;        // wave id 0..3 -> x-row strip w*32
    const int l15  = lane & 15;
    const int lg   = lane >> 4;     // 0..3 -> k-slot group

    f16x8 xh[2][2], xl[2][2];       // [i = row sub-tile][kh = k half]
    float xsq[2];
#pragma unroll
    for (int i = 0; i < 2; ++i) {
        const float* xp = x + (size_t)(row0 + w * 32 + i * 16 + l15) * D + lg * 8;
        float s = 0.f;
#pragma unroll
        for (int kh = 0; kh < 2; ++kh) {
            float4 a0 = *reinterpret_cast<const float4*>(xp + kh * 32);
            float4 a1 = *reinterpret_cast<const float4*>(xp + kh * 32 + 4);
            float v[8] = {a0.x, a0.y, a0.z, a0.w, a1.x, a1.y, a1.z, a1.w};
#pragma unroll
            for (int j = 0; j < 8; ++j) {
                _Float16 hh = (_Float16)v[j];
                xh[i][kh][j] = hh;
                xl[i][kh][j] = (_Float16)(v[j] - (float)hh);
                s = fmaf(v[j], v[j], s);
            }
        }
        // lanes {l15, l15+16, l15+32, l15+48} hold disjoint k-slices of the
        // same x row -> butterfly over lg bits gives the full ||x_row||^2.
        s += __shfl_xor(s, 16);
        s += __shfl_xor(s, 32);
        xsq[i] = s;
    }
    __syncthreads();

    // ---- MFMA main: A = y (LDS), B = x (reg); 96 MFMAs / wave ------------
    f32x4 acc[2][8];
#pragma unroll
    for (int i = 0; i < 2; ++i)
#pragma unroll
        for (int nt = 0; nt < 8; ++nt) acc[i][nt] = (f32x4){0.f, 0.f, 0.f, 0.f};

    const int swzA = (l15 & 7) << 4;
#pragma unroll
    for (int kh = 0; kh < 2; ++kh) {
        const int dsw = (kh * 64 + lg * 16) ^ swzA;
#pragma unroll
        for (int nt = 0; nt < 8; ++nt) {
            const int aoff = (nt * 16 + l15) * 128 + dsw;
            f16x8 yh = *reinterpret_cast<const f16x8*>(YH + aoff);
            f16x8 yl = *reinterpret_cast<const f16x8*>(YL + aoff);
            acc[0][nt] = __builtin_amdgcn_mfma_f32_16x16x32_f16(yh, xh[0][kh], acc[0][nt], 0, 0, 0);
            acc[1][nt] = __builtin_amdgcn_mfma_f32_16x16x32_f16(yh, xh[1][kh], acc[1][nt], 0, 0, 0);
            acc[0][nt] = __builtin_amdgcn_mfma_f32_16x16x32_f16(yl, xh[0][kh], acc[0][nt], 0, 0, 0);
            acc[1][nt] = __builtin_amdgcn_mfma_f32_16x16x32_f16(yl, xh[1][kh], acc[1][nt], 0, 0, 0);
            acc[0][nt] = __builtin_amdgcn_mfma_f32_16x16x32_f16(yh, xl[0][kh], acc[0][nt], 0, 0, 0);
            acc[1][nt] = __builtin_amdgcn_mfma_f32_16x16x32_f16(yh, xl[1][kh], acc[1][nt], 0, 0, 0);
        }
    }

    // ---- epilogue: dist^2 -> exp -> float4 stores ------------------------
#pragma unroll
    for (int nt = 0; nt < 8; ++nt) {
        const int c = nt * 16 + lg * 4;
        float4 p0 = *reinterpret_cast<const float4*>(&Ysq0[c]);
        float4 p1 = *reinterpret_cast<const float4*>(&Ysq1[c]);
        float ysqv[4] = {p0.x + p1.x, p0.y + p1.y, p0.z + p1.z, p0.w + p1.w};
#pragma unroll
        for (int i = 0; i < 2; ++i) {
            const int rowg = row0 + w * 32 + i * 16 + l15;
            float e[4];
#pragma unroll
            for (int r = 0; r < 4; ++r) {
                float d2 = fmaf(-2.f, acc[i][nt][r], xsq[i] + ysqv[r]);
                d2 = fmaxf(d2, 0.f);
                e[r] = __expf(-d2);
            }
            *reinterpret_cast<float4*>(out + (size_t)rowg * NROW + col0 + c) =
                make_float4(e[0], e[1], e[2], e[3]);
        }
    }
}

extern "C" void kernel_launch(void* const* d_in, const int* in_sizes, int n_in,
                              void* d_out, int out_size, void* d_ws, size_t ws_size,
                              hipStream_t stream) {
    const float* x = (const float*)d_in[0];
    const float* y = (const float*)d_in[1];
    float* out = (float*)d_out;
    (void)d_ws; (void)ws_size;

    rbf_fused<<<dim3(NROW / 128, NROW / 128), 256, 0, stream>>>(x, y, out);
}